// Round 3
// baseline (460.943 us; speedup 1.0000x reference)
//
#include <hip/hip_runtime.h>
#include <hip/hip_bf16.h>

// StochasticTernaryLinear: out = x @ ((sign(wp)-sign(wn))*0.5).T + bias
// B=524288, IN_F=128, OUT_F=128, all fp32 in/out.
// Strategy: ternarize weights to bf16 once into d_ws, then bf16-MFMA GEMM,
// fp32 accumulate, no LDS (fragment-direct global loads).

typedef short short8 __attribute__((ext_vector_type(8)));
typedef float f32x4 __attribute__((ext_vector_type(4)));
typedef float f32x8 __attribute__((ext_vector_type(8)));

// fp32 -> bf16 bits, round-to-nearest-even (inputs are finite normals)
__device__ __forceinline__ short f2bf(float f) {
  unsigned u = __builtin_bit_cast(unsigned, f);
  unsigned r = u + 0x7fffu + ((u >> 16) & 1u);
  return (short)(r >> 16);
}

__global__ void ternarize_kernel(const float* __restrict__ wp,
                                 const float* __restrict__ wn,
                                 short* __restrict__ wt, int n) {
  int i = blockIdx.x * blockDim.x + threadIdx.x;
  if (i < n) {
    float p = wp[i];
    float q = wn[i];
    // (sign(p) - sign(q)) * 0.5 with sign(v) = (v >= 0 ? +1 : -1)
    float v = 0.5f * ((p >= 0.f ? 1.f : -1.f) - (q >= 0.f ? 1.f : -1.f));
    wt[i] = f2bf(v);  // exactly -1, 0, +1 in bf16
  }
}

// Block: 256 threads = 4 waves. Block tile: 128 rows x 128 cols.
// Wave w: rows [blk*128 + w*32, +32) as 2 row-fragments (m) x 8 col-fragments (c).
// MFMA 16x16x32 bf16; K=128 -> 4 K-steps.
__launch_bounds__(256)
__global__ void stl_gemm_kernel(const float* __restrict__ x,
                                const short* __restrict__ wt,   // bf16 bits [128][128]
                                const float* __restrict__ bias,
                                float* __restrict__ out) {
  constexpr int IN_F = 128;
  constexpr int OUT_F = 128;
  const int wave = threadIdx.x >> 6;
  const int lane = threadIdx.x & 63;
  const int r = lane & 15;   // A: x-row within 16; B: out-col within 16; D: col
  const int g = lane >> 4;   // k-group (A/B), row-group (D)
  const long row0 = (long)blockIdx.x * 128 + wave * 32;

  f32x4 acc[2][8] = {};  // [m][c]

#pragma unroll
  for (int kk = 0; kk < 4; ++kk) {
    const int k0 = kk * 32 + g * 8;
    short8 a[2];
    short8 b[8];
#pragma unroll
    for (int m = 0; m < 2; ++m) {
      // 8 consecutive fp32 (32B) per lane, in exact A-fragment layout
      f32x8 xv = *(const f32x8*)(x + (row0 + m * 16 + r) * IN_F + k0);
#pragma unroll
      for (int j = 0; j < 8; ++j) a[m][j] = f2bf(xv[j]);
    }
#pragma unroll
    for (int c = 0; c < 8; ++c) {
      // B[k][n] = w[n][k]: same lane pattern as A, from bf16 weight scratch
      b[c] = *(const short8*)(wt + (c * 16 + r) * IN_F + k0);
    }
#pragma unroll
    for (int m = 0; m < 2; ++m)
#pragma unroll
      for (int c = 0; c < 8; ++c)
        acc[m][c] =
            __builtin_amdgcn_mfma_f32_16x16x32_bf16(a[m], b[c], acc[m][c], 0, 0, 0);
  }

  // Epilogue: D mapping col = lane&15, row = (lane>>4)*4 + reg  [m89-verified]
#pragma unroll
  for (int c = 0; c < 8; ++c) {
    const float bv = bias[c * 16 + r];
#pragma unroll
    for (int m = 0; m < 2; ++m) {
      const long orow = row0 + m * 16 + g * 4;
#pragma unroll
      for (int reg = 0; reg < 4; ++reg) {
        out[(orow + reg) * OUT_F + c * 16 + r] = acc[m][c][reg] + bv;
      }
    }
  }
}

extern "C" void kernel_launch(void* const* d_in, const int* in_sizes, int n_in,
                              void* d_out, int out_size, void* d_ws, size_t ws_size,
                              hipStream_t stream) {
  const float* x    = (const float*)d_in[0];
  const float* wp   = (const float*)d_in[1];
  const float* wn   = (const float*)d_in[2];
  const float* bias = (const float*)d_in[3];
  float* out = (float*)d_out;
  short* wt = (short*)d_ws;  // 128*128 bf16 = 32 KB scratch

  ternarize_kernel<<<64, 256, 0, stream>>>(wp, wn, wt, 128 * 128);

  // 524288 rows / 128 rows-per-block = 4096 blocks (exact, no tail)
  stl_gemm_kernel<<<4096, 256, 0, stream>>>(x, wt, bias, out);
}